// Round 1
// baseline (2485.380 us; speedup 1.0000x reference)
//
#include <hip/hip_runtime.h>
#include <cstdint>
#include <cstddef>

#define BB 64
#define NN 512
#define DD 768
#define KB 64
#define NSTEP (NN/KB)

// m value: mask is 0.0 (valid) or -10000.0 (pad) -> m = mask * -1e-4 = 0 or 1 exactly.

__device__ __forceinline__ float aval(float adjv, float mi, float mj) {
    return expf(fmaxf(adjv - 50.f * (mi + mj), -40.f));
}

// ---------------- root / R ----------------
__global__ void k_root(const float* __restrict__ x, const float* __restrict__ mask,
                       const float* __restrict__ w, const float* __restrict__ br,
                       float* __restrict__ R) {
    int wave = threadIdx.x >> 6, lane = threadIdx.x & 63;
    int row = blockIdx.x * 4 + wave;           // b*NN + n
    const float* xr = x + (size_t)row * DD;
    float s = 0.f;
#pragma unroll
    for (int k = 0; k < DD / 64; ++k) s += xr[k * 64 + lane] * w[k * 64 + lane];
    for (int off = 32; off; off >>= 1) s += __shfl_down(s, off, 64);
    if (lane == 0) {
        float m = mask[row] * -1e-4f;
        float rv = fmaxf(s + br[0] - 50.f * m, -40.f);
        R[row] = expf(rv);
    }
}

// ---------------- column sums of A (partials) ----------------
__global__ void k_colsum(const float* __restrict__ adj, const float* __restrict__ mask,
                         double* __restrict__ Lp) {
    int b = blockIdx.x, chunk = blockIdx.y;
    int j = threadIdx.x;                        // 512
    float mj = mask[b * NN + j] * -1e-4f;
    const float* ab = adj + (size_t)b * NN * NN;
    double acc = 0.0;
    int i0 = chunk * 128;
    for (int i = i0; i < i0 + 128; ++i) {
        float mi = mask[b * NN + i] * -1e-4f;
        acc += (double)aval(ab[(size_t)i * NN + j], mi, mj);
    }
    Lp[((size_t)b * 4 + chunk) * NN + j] = acc;
}

// ---------------- build LL ----------------
template <typename T>
__global__ void k_build(const float* __restrict__ adj, const float* __restrict__ mask,
                        const float* __restrict__ R, const double* __restrict__ Lp,
                        T* __restrict__ M) {
    int b = blockIdx.x >> 9;
    int r = blockIdx.x & 511;
    int c = threadIdx.x;                        // 512
    float mr = mask[b * NN + r] * -1e-4f;
    float mc = mask[b * NN + c] * -1e-4f;
    size_t idx = ((size_t)b * NN + r) * NN + c;
    float a = aval(adj[idx], mr, mc);
    T v;
    if (r == c) {
        const double* lp = Lp + (size_t)b * 4 * NN;
        double L = lp[c] + lp[NN + c] + lp[2 * NN + c] + lp[3 * NN + c];
        v = (T)(L - (double)a + (double)R[b * NN + c]);
    } else {
        v = (T)(-a);
    }
    M[idx] = v;
}

// ---------------- save column panel ----------------
template <typename T>
__global__ void k_savecol(const T* __restrict__ M, T* __restrict__ Cb, int k0) {
    int t = threadIdx.x;
    int c = t & 63, rr = t >> 6;
    int row = blockIdx.x * 4 + rr;              // b*NN + i
    int b = row >> 9, i = row & 511;
    Cb[(size_t)row * KB + c] = M[((size_t)b * NN + i) * NN + k0 + c];
}

// ---------------- invert 64x64 pivot block (in registers + LDS, f64) ----------------
template <typename T>
__global__ void k_invblk(const T* __restrict__ M, T* __restrict__ Bb, int k0) {
    __shared__ double pr[KB];
    __shared__ double fv[KB];
    __shared__ double pvt;
    int b = blockIdx.x;
    int r = threadIdx.x & 63, q = threadIdx.x >> 6;   // thread owns row r, cols q*16..q*16+15
    double a[16];
    const T* Mb = M + ((size_t)b * NN + k0) * NN + k0;
#pragma unroll
    for (int c = 0; c < 16; ++c) a[c] = (double)Mb[(size_t)r * NN + q * 16 + c];
    for (int k = 0; k < KB; ++k) {
        int kq = k >> 4, kc = k & 15;
        if (r == k && q == kq) pvt = a[kc];
        __syncthreads();
        double ip = 1.0 / pvt;
        if (r == k) {
#pragma unroll
            for (int c = 0; c < 16; ++c) a[c] *= ip;
            if (q == kq) a[kc] = ip;
#pragma unroll
            for (int c = 0; c < 16; ++c) pr[q * 16 + c] = a[c];
        }
        if (r != k && q == kq) fv[r] = a[kc];
        __syncthreads();
        if (r != k) {
            double f = fv[r];
#pragma unroll
            for (int c = 0; c < 16; ++c) a[c] -= f * pr[q * 16 + c];
            if (q == kq) a[kc] = -f * ip;
        }
        __syncthreads();
    }
    T* Bo = Bb + (size_t)b * KB * KB;
#pragma unroll
    for (int c = 0; c < 16; ++c) Bo[r * KB + q * 16 + c] = (T)a[c];
}

// ---------------- pivot rows: M[k0:k0+64, :] = Binv @ Mold ----------------
template <typename T>
__global__ void k_pivrows(T* __restrict__ M, const T* __restrict__ Bb, int k0) {
    __shared__ double Bi[KB][KB];
    __shared__ double Mt[KB][KB + 1];
    int b = blockIdx.x, jt = blockIdx.y * 64;
    const T* Bo = Bb + (size_t)b * KB * KB;
    T* Mb = M + ((size_t)b * NN + k0) * NN;
    int t = threadIdx.x;
    for (int e = t; e < KB * KB; e += 256) {
        int rr = e >> 6, cc = e & 63;
        Bi[rr][cc] = (double)Bo[e];
        Mt[rr][cc] = (double)Mb[(size_t)rr * NN + jt + cc];
    }
    __syncthreads();
    if (blockIdx.y == (unsigned)(k0 >> 6)) {
        for (int e = t; e < KB * KB; e += 256) {
            int rr = e >> 6, cc = e & 63;
            Mb[(size_t)rr * NN + jt + cc] = (T)Bi[rr][cc];
        }
        return;
    }
    int tx = t & 15, ty = t >> 4;
    double acc[4][4] = {};
    for (int k = 0; k < KB; ++k) {
        double av[4], bv[4];
#pragma unroll
        for (int u = 0; u < 4; ++u) { av[u] = Bi[ty * 4 + u][k]; bv[u] = Mt[k][tx * 4 + u]; }
#pragma unroll
        for (int u = 0; u < 4; ++u)
#pragma unroll
            for (int v = 0; v < 4; ++v) acc[u][v] += av[u] * bv[v];
    }
#pragma unroll
    for (int u = 0; u < 4; ++u)
#pragma unroll
        for (int v = 0; v < 4; ++v)
            Mb[(size_t)(ty * 4 + u) * NN + jt + tx * 4 + v] = (T)acc[u][v];
}

// ---------------- rank-64 update: M[i,:] -= C[i,:] @ Rnew, block cols extra -C ----------------
template <typename T>
__global__ void k_update(T* __restrict__ M, const T* __restrict__ Cb, int k0) {
    int step = k0 >> 6;
    int it = blockIdx.y;
    if (it == step) return;
    int b = blockIdx.x, jt = blockIdx.z;
    __shared__ double Ct[KB][KB + 1];
    __shared__ double Rt[KB][KB + 1];
    int t = threadIdx.x;
    const T* Cbb = Cb + ((size_t)b * NN + it * 64) * KB;
    const T* Rb  = M + ((size_t)b * NN + k0) * NN + jt * 64;
    for (int e = t; e < KB * KB; e += 256) {
        int rr = e >> 6, cc = e & 63;
        Ct[rr][cc] = (double)Cbb[(size_t)rr * KB + cc];
        Rt[rr][cc] = (double)Rb[(size_t)rr * NN + cc];
    }
    __syncthreads();
    int tx = t & 15, ty = t >> 4;
    double acc[4][4] = {};
    for (int k = 0; k < KB; ++k) {
        double av[4], bv[4];
#pragma unroll
        for (int u = 0; u < 4; ++u) { av[u] = Ct[ty * 4 + u][k]; bv[u] = Rt[k][tx * 4 + u]; }
#pragma unroll
        for (int u = 0; u < 4; ++u)
#pragma unroll
            for (int v = 0; v < 4; ++v) acc[u][v] += av[u] * bv[v];
    }
    T* Mo = M + ((size_t)b * NN + it * 64) * NN + jt * 64;
    bool blockcol = (jt == step);
#pragma unroll
    for (int u = 0; u < 4; ++u) {
        int row = ty * 4 + u;
#pragma unroll
        for (int v = 0; v < 4; ++v) {
            int col = tx * 4 + v;
            double val = (double)Mo[(size_t)row * NN + col] - acc[u][v];
            if (blockcol) val -= Ct[row][col];
            Mo[(size_t)row * NN + col] = (T)val;
        }
    }
}

// ---------------- diag extraction + BCE loss partials ----------------
template <typename T>
__global__ void k_dgloss(const T* __restrict__ M, const float* __restrict__ R,
                         const float* __restrict__ rlab, const int* __restrict__ rmask,
                         double* __restrict__ Dg, float* __restrict__ lossp) {
    int idx = blockIdx.x * 256 + threadIdx.x;   // b*NN + n
    int b = idx >> 9, n = idx & 511;
    double xv = (double)M[((size_t)b * NN + n) * NN + n];
    Dg[idx] = xv;
    float d0 = R[idx] * (float)xv;
    float lg = fminf(fmaxf(d0, 1e-5f), 1.f - 1e-5f);
    float rm = (float)rmask[idx];
    float lab = (rmask[idx] == 1) ? rlab[idx] : 0.f;
    float bce = -(lab * logf(lg) + (1.f - lab) * logf(1.f - lg));
    __shared__ double sm[256];
    sm[threadIdx.x] = (double)(bce * rm);
    __syncthreads();
    for (int s = 128; s; s >>= 1) {
        if (threadIdx.x < s) sm[threadIdx.x] += sm[threadIdx.x + s];
        __syncthreads();
    }
    if (threadIdx.x == 0) lossp[blockIdx.x] = (float)sm[0];
}

__global__ void k_lossfin(const float* __restrict__ lossp, float* __restrict__ outv) {
    __shared__ double sm[128];
    sm[threadIdx.x] = (double)lossp[threadIdx.x];
    __syncthreads();
    for (int s = 64; s; s >>= 1) {
        if (threadIdx.x < s) sm[threadIdx.x] += sm[threadIdx.x + s];
        __syncthreads();
    }
    if (threadIdx.x == 0) outv[0] = (float)(sm[0] / (double)(BB * NN));
}

// ---------------- d = A .* (diag(X)[j] - X[j,i]) ----------------
template <typename T>
__global__ void k_d(const T* __restrict__ M, const double* __restrict__ Dg,
                    const float* __restrict__ adj, const float* __restrict__ mask,
                    float* __restrict__ dout) {
    int b = blockIdx.x, i0 = blockIdx.y * 64, j0 = blockIdx.z * 64;
    __shared__ double Xt[64][65];
    int t = threadIdx.x, ii = t & 63, jj0 = t >> 6;
    const T* Mb = M + (size_t)b * NN * NN;
    for (int jj = jj0; jj < 64; jj += 4)
        Xt[jj][ii] = (double)Mb[(size_t)(j0 + jj) * NN + i0 + ii];
    __syncthreads();
    int jc = t & 63, ir0 = t >> 6;
    float mj = mask[b * NN + j0 + jc] * -1e-4f;
    double dg = Dg[b * NN + j0 + jc];
    const float* ab = adj + (size_t)b * NN * NN;
    float* db = dout + (size_t)b * NN * NN;
    for (int ir = ir0; ir < 64; ir += 4) {
        int i = i0 + ir;
        float mi = mask[b * NN + i] * -1e-4f;
        float a = aval(ab[(size_t)i * NN + j0 + jc], mi, mj);
        db[(size_t)i * NN + j0 + jc] = a * (float)(dg - Xt[jc][ir]);
    }
}

// ---------------- context = (masked d^T) @ x ----------------
__global__ void k_ctx(const float* __restrict__ dmat, const float* __restrict__ x,
                      const float* __restrict__ mask, float* __restrict__ ctx) {
    int b = blockIdx.x, i0 = blockIdx.y * 64, c0 = blockIdx.z * 64;
    __shared__ float At[32][65];
    __shared__ float Xl[32][65];
    int t = threadIdx.x;
    int tx = t & 15, ty = t >> 4;
    float acc[4][4] = {};
    const float* db = dmat + (size_t)b * NN * NN;
    const float* xb = x + (size_t)b * NN * DD;
    int li = t & 63, lk = t >> 6;
    for (int kt = 0; kt < NN; kt += 32) {
#pragma unroll
        for (int rep = 0; rep < 8; ++rep) {
            int kk = lk + rep * 4;
            float mk = mask[b * NN + kt + kk] * -1e-4f;
            float v = db[(size_t)(kt + kk) * NN + i0 + li];
            At[kk][li] = (mk > 0.5f) ? 0.f : v;
            Xl[kk][li] = xb[(size_t)(kt + kk) * DD + c0 + li];
        }
        __syncthreads();
        for (int kk = 0; kk < 32; ++kk) {
            float av[4], bv[4];
#pragma unroll
            for (int u = 0; u < 4; ++u) { av[u] = At[kk][ty * 4 + u]; bv[u] = Xl[kk][tx * 4 + u]; }
#pragma unroll
            for (int u = 0; u < 4; ++u)
#pragma unroll
                for (int v = 0; v < 4; ++v) acc[u][v] += av[u] * bv[v];
        }
        __syncthreads();
    }
    float* cb = ctx + (size_t)b * NN * DD;
#pragma unroll
    for (int u = 0; u < 4; ++u)
#pragma unroll
        for (int v = 0; v < 4; ++v)
            cb[(size_t)(i0 + ty * 4 + u) * DD + c0 + tx * 4 + v] = acc[u][v];
}

// ---------------- driver ----------------
template <typename T>
static void run_all(const float* x, const float* adj, const float* mask,
                    const float* rlab, const int* rmask, const float* w, const float* br,
                    float* ctx, float* dmat, float* lossout,
                    char* ws, hipStream_t stream) {
    size_t off = 0;
    T* M  = (T*)(ws + off); off += (size_t)BB * NN * NN * sizeof(T);
    T* Cb = (T*)(ws + off); off += (size_t)BB * NN * KB * sizeof(T);
    T* Bb = (T*)(ws + off); off += (size_t)BB * KB * KB * sizeof(T);
    double* Lp = (double*)(ws + off); off += (size_t)BB * 4 * NN * 8;
    float* Rf  = (float*)(ws + off);  off += (size_t)BB * NN * 4;
    double* Dg = (double*)(ws + off); off += (size_t)BB * NN * 8;
    float* lossp = (float*)(ws + off);

    k_root<<<BB * NN / 4, 256, 0, stream>>>(x, mask, w, br, Rf);
    k_colsum<<<dim3(BB, 4), 512, 0, stream>>>(adj, mask, Lp);
    k_build<T><<<BB * NN, 512, 0, stream>>>(adj, mask, Rf, Lp, M);
    for (int s = 0; s < NSTEP; ++s) {
        int k0 = s * KB;
        k_savecol<T><<<BB * NN / 4, 256, 0, stream>>>(M, Cb, k0);
        k_invblk<T><<<BB, 256, 0, stream>>>(M, Bb, k0);
        k_pivrows<T><<<dim3(BB, 8), 256, 0, stream>>>(M, Bb, k0);
        k_update<T><<<dim3(BB, 8, 8), 256, 0, stream>>>(M, Cb, k0);
    }
    k_dgloss<T><<<BB * NN / 256, 256, 0, stream>>>(M, Rf, rlab, rmask, Dg, lossp);
    k_lossfin<<<1, 128, 0, stream>>>(lossp, lossout);
    k_d<T><<<dim3(BB, 8, 8), 256, 0, stream>>>(M, Dg, adj, mask, dmat);
    k_ctx<<<dim3(BB, 8, 12), 256, 0, stream>>>(dmat, x, mask, ctx);
}

extern "C" void kernel_launch(void* const* d_in, const int* in_sizes, int n_in,
                              void* d_out, int out_size, void* d_ws, size_t ws_size,
                              hipStream_t stream) {
    const float* x    = (const float*)d_in[0];
    const float* adj  = (const float*)d_in[1];
    const float* mask = (const float*)d_in[2];
    const float* rlab = (const float*)d_in[3];
    const int*   rmask= (const int*)d_in[4];
    const float* w    = (const float*)d_in[5];
    const float* br   = (const float*)d_in[6];
    float* out = (float*)d_out;
    float* ctx = out;
    float* dmat = out + (size_t)BB * NN * DD;
    float* lossout = dmat + (size_t)BB * NN * NN;
    char* ws = (char*)d_ws;

    size_t needD = (size_t)BB * NN * NN * 8 + (size_t)BB * NN * KB * 8 + (size_t)BB * KB * KB * 8
                 + (size_t)BB * 4 * NN * 8 + (size_t)BB * NN * 4 + (size_t)BB * NN * 8 + 4096;
    if (ws_size >= needD)
        run_all<double>(x, adj, mask, rlab, rmask, w, br, ctx, dmat, lossout, ws, stream);
    else
        run_all<float>(x, adj, mask, rlab, rmask, w, br, ctx, dmat, lossout, ws, stream);
}

// Round 2
// 2182.668 us; speedup vs baseline: 1.1387x; 1.1387x over previous
//
#include <hip/hip_runtime.h>
#include <cstdint>
#include <cstddef>

#define BB 64
#define NN 512
#define DD 768
#define KB 64
#define NSTEP (NN/KB)

typedef __bf16 bf16x8 __attribute__((ext_vector_type(8)));
typedef float f32x4 __attribute__((ext_vector_type(4)));
typedef unsigned short us8 __attribute__((ext_vector_type(8)));

__device__ __forceinline__ float aval(float adjv, float mi, float mj) {
    return expf(fmaxf(adjv - 50.f * (mi + mj), -40.f));
}

__device__ __forceinline__ unsigned short f2bf(float v) {
    union { float f; unsigned int u; } c; c.f = v;
    return (unsigned short)((c.u + 0x7fffu + ((c.u >> 16) & 1u)) >> 16);
}
__device__ __forceinline__ float bf2f(unsigned short h) {
    union { unsigned int u; float f; } c; c.u = ((unsigned int)h) << 16;
    return c.f;
}

__device__ __forceinline__ void gl_lds16(const void* g, void* l) {
    __builtin_amdgcn_global_load_lds((const __attribute__((address_space(1))) unsigned int*)g,
                                     (__attribute__((address_space(3))) unsigned int*)l, 16, 0, 0);
}

// ---------------- root / R ----------------
__global__ void k_root(const float* __restrict__ x, const float* __restrict__ mask,
                       const float* __restrict__ w, const float* __restrict__ br,
                       float* __restrict__ R) {
    int wave = threadIdx.x >> 6, lane = threadIdx.x & 63;
    int row = blockIdx.x * 4 + wave;           // b*NN + n
    const float* xr = x + (size_t)row * DD;
    float s = 0.f;
#pragma unroll
    for (int k = 0; k < DD / 64; ++k) s += xr[k * 64 + lane] * w[k * 64 + lane];
    for (int off = 32; off; off >>= 1) s += __shfl_down(s, off, 64);
    if (lane == 0) {
        float m = mask[row] * -1e-4f;
        float rv = fmaxf(s + br[0] - 50.f * m, -40.f);
        R[row] = expf(rv);
    }
}

// ---------------- column sums of A (partials) ----------------
__global__ void k_colsum(const float* __restrict__ adj, const float* __restrict__ mask,
                         double* __restrict__ Lp) {
    int b = blockIdx.x, chunk = blockIdx.y;
    int j = threadIdx.x;                        // 512
    float mj = mask[b * NN + j] * -1e-4f;
    const float* ab = adj + (size_t)b * NN * NN;
    double acc = 0.0;
    int i0 = chunk * 128;
    for (int i = i0; i < i0 + 128; ++i) {
        float mi = mask[b * NN + i] * -1e-4f;
        acc += (double)aval(ab[(size_t)i * NN + j], mi, mj);
    }
    Lp[((size_t)b * 4 + chunk) * NN + j] = acc;
}

// ---------------- build LL ----------------
template <typename T>
__global__ void k_build(const float* __restrict__ adj, const float* __restrict__ mask,
                        const float* __restrict__ R, const double* __restrict__ Lp,
                        T* __restrict__ M) {
    int b = blockIdx.x >> 9;
    int r = blockIdx.x & 511;
    int c = threadIdx.x;                        // 512
    float mr = mask[b * NN + r] * -1e-4f;
    float mc = mask[b * NN + c] * -1e-4f;
    size_t idx = ((size_t)b * NN + r) * NN + c;
    float a = aval(adj[idx], mr, mc);
    T v;
    if (r == c) {
        const double* lp = Lp + (size_t)b * 4 * NN;
        double L = lp[c] + lp[NN + c] + lp[2 * NN + c] + lp[3 * NN + c];
        v = (T)(L - (double)a + (double)R[b * NN + c]);
    } else {
        v = (T)(-a);
    }
    M[idx] = v;
}

// ---------------- save column panel ----------------
template <typename T>
__global__ void k_savecol(const T* __restrict__ M, T* __restrict__ Cb, int k0) {
    int t = threadIdx.x;
    int c = t & 63, rr = t >> 6;
    int row = blockIdx.x * 4 + rr;              // b*NN + i
    int b = row >> 9, i = row & 511;
    Cb[(size_t)row * KB + c] = M[((size_t)b * NN + i) * NN + k0 + c];
}

// ---------------- invert 64x64 pivot block ----------------
template <typename T>
__global__ void k_invblk(const T* __restrict__ M, T* __restrict__ Bb, int k0) {
    __shared__ double pr[KB];
    __shared__ double fv[KB];
    __shared__ double pvt;
    int b = blockIdx.x;
    int r = threadIdx.x & 63, q = threadIdx.x >> 6;
    double a[16];
    const T* Mb = M + ((size_t)b * NN + k0) * NN + k0;
#pragma unroll
    for (int c = 0; c < 16; ++c) a[c] = (double)Mb[(size_t)r * NN + q * 16 + c];
    for (int k = 0; k < KB; ++k) {
        int kq = k >> 4, kc = k & 15;
        if (r == k && q == kq) pvt = a[kc];
        __syncthreads();
        double ip = 1.0 / pvt;
        if (r == k) {
#pragma unroll
            for (int c = 0; c < 16; ++c) a[c] *= ip;
            if (q == kq) a[kc] = ip;
#pragma unroll
            for (int c = 0; c < 16; ++c) pr[q * 16 + c] = a[c];
        }
        if (r != k && q == kq) fv[r] = a[kc];
        __syncthreads();
        if (r != k) {
            double f = fv[r];
#pragma unroll
            for (int c = 0; c < 16; ++c) a[c] -= f * pr[q * 16 + c];
            if (q == kq) a[kc] = -f * ip;
        }
        __syncthreads();
    }
    T* Bo = Bb + (size_t)b * KB * KB;
#pragma unroll
    for (int c = 0; c < 16; ++c) Bo[r * KB + q * 16 + c] = (T)a[c];
}

// ---------------- pivot rows: M[k0:k0+64, :] = Binv @ Mold ----------------
template <typename T>
__global__ void k_pivrows(T* __restrict__ M, const T* __restrict__ Bb, int k0) {
    __shared__ double Bi[KB][KB];
    __shared__ double Mt[KB][KB + 1];
    int b = blockIdx.x, jt = blockIdx.y * 64;
    const T* Bo = Bb + (size_t)b * KB * KB;
    T* Mb = M + ((size_t)b * NN + k0) * NN;
    int t = threadIdx.x;
    for (int e = t; e < KB * KB; e += 256) {
        int rr = e >> 6, cc = e & 63;
        Bi[rr][cc] = (double)Bo[e];
        Mt[rr][cc] = (double)Mb[(size_t)rr * NN + jt + cc];
    }
    __syncthreads();
    if (blockIdx.y == (unsigned)(k0 >> 6)) {
        for (int e = t; e < KB * KB; e += 256) {
            int rr = e >> 6, cc = e & 63;
            Mb[(size_t)rr * NN + jt + cc] = (T)Bi[rr][cc];
        }
        return;
    }
    int tx = t & 15, ty = t >> 4;
    double acc[4][4] = {};
    for (int k = 0; k < KB; ++k) {
        double av[4], bv[4];
#pragma unroll
        for (int u = 0; u < 4; ++u) { av[u] = Bi[ty * 4 + u][k]; bv[u] = Mt[k][tx * 4 + u]; }
#pragma unroll
        for (int u = 0; u < 4; ++u)
#pragma unroll
            for (int v = 0; v < 4; ++v) acc[u][v] += av[u] * bv[v];
    }
#pragma unroll
    for (int u = 0; u < 4; ++u)
#pragma unroll
        for (int v = 0; v < 4; ++v)
            Mb[(size_t)(ty * 4 + u) * NN + jt + tx * 4 + v] = (T)acc[u][v];
}

// ---------------- rank-64 update ----------------
template <typename T>
__global__ void k_update(T* __restrict__ M, const T* __restrict__ Cb, int k0) {
    int step = k0 >> 6;
    int it = blockIdx.y;
    if (it == step) return;
    int b = blockIdx.x, jt = blockIdx.z;
    __shared__ double Ct[KB][KB + 1];
    __shared__ double Rt[KB][KB + 1];
    int t = threadIdx.x;
    const T* Cbb = Cb + ((size_t)b * NN + it * 64) * KB;
    const T* Rb  = M + ((size_t)b * NN + k0) * NN + jt * 64;
    for (int e = t; e < KB * KB; e += 256) {
        int rr = e >> 6, cc = e & 63;
        Ct[rr][cc] = (double)Cbb[(size_t)rr * KB + cc];
        Rt[rr][cc] = (double)Rb[(size_t)rr * NN + cc];
    }
    __syncthreads();
    int tx = t & 15, ty = t >> 4;
    double acc[4][4] = {};
    for (int k = 0; k < KB; ++k) {
        double av[4], bv[4];
#pragma unroll
        for (int u = 0; u < 4; ++u) { av[u] = Ct[ty * 4 + u][k]; bv[u] = Rt[k][tx * 4 + u]; }
#pragma unroll
        for (int u = 0; u < 4; ++u)
#pragma unroll
            for (int v = 0; v < 4; ++v) acc[u][v] += av[u] * bv[v];
    }
    T* Mo = M + ((size_t)b * NN + it * 64) * NN + jt * 64;
    bool blockcol = (jt == step);
#pragma unroll
    for (int u = 0; u < 4; ++u) {
        int row = ty * 4 + u;
#pragma unroll
        for (int v = 0; v < 4; ++v) {
            int col = tx * 4 + v;
            double val = (double)Mo[(size_t)row * NN + col] - acc[u][v];
            if (blockcol) val -= Ct[row][col];
            Mo[(size_t)row * NN + col] = (T)val;
        }
    }
}

// ---------------- diag extraction + BCE loss partials ----------------
template <typename T>
__global__ void k_dgloss(const T* __restrict__ M, const float* __restrict__ R,
                         const float* __restrict__ rlab, const int* __restrict__ rmask,
                         double* __restrict__ Dg, float* __restrict__ lossp) {
    int idx = blockIdx.x * 256 + threadIdx.x;
    int b = idx >> 9, n = idx & 511;
    double xv = (double)M[((size_t)b * NN + n) * NN + n];
    Dg[idx] = xv;
    float d0 = R[idx] * (float)xv;
    float lg = fminf(fmaxf(d0, 1e-5f), 1.f - 1e-5f);
    float rm = (float)rmask[idx];
    float lab = (rmask[idx] == 1) ? rlab[idx] : 0.f;
    float bce = -(lab * logf(lg) + (1.f - lab) * logf(1.f - lg));
    __shared__ double sm[256];
    sm[threadIdx.x] = (double)(bce * rm);
    __syncthreads();
    for (int s = 128; s; s >>= 1) {
        if (threadIdx.x < s) sm[threadIdx.x] += sm[threadIdx.x + s];
        __syncthreads();
    }
    if (threadIdx.x == 0) lossp[blockIdx.x] = (float)sm[0];
}

__global__ void k_lossfin(const float* __restrict__ lossp, float* __restrict__ outv) {
    __shared__ double sm[128];
    sm[threadIdx.x] = (double)lossp[threadIdx.x];
    __syncthreads();
    for (int s = 64; s; s >>= 1) {
        if (threadIdx.x < s) sm[threadIdx.x] += sm[threadIdx.x + s];
        __syncthreads();
    }
    if (threadIdx.x == 0) outv[0] = (float)(sm[0] / (double)(BB * NN));
}

// ---------------- d (old, fallback) ----------------
template <typename T>
__global__ void k_d(const T* __restrict__ M, const double* __restrict__ Dg,
                    const float* __restrict__ adj, const float* __restrict__ mask,
                    float* __restrict__ dout) {
    int b = blockIdx.x, i0 = blockIdx.y * 64, j0 = blockIdx.z * 64;
    __shared__ double Xt[64][65];
    int t = threadIdx.x, ii = t & 63, jj0 = t >> 6;
    const T* Mb = M + (size_t)b * NN * NN;
    for (int jj = jj0; jj < 64; jj += 4)
        Xt[jj][ii] = (double)Mb[(size_t)(j0 + jj) * NN + i0 + ii];
    __syncthreads();
    int jc = t & 63, ir0 = t >> 6;
    float mj = mask[b * NN + j0 + jc] * -1e-4f;
    double dg = Dg[b * NN + j0 + jc];
    const float* ab = adj + (size_t)b * NN * NN;
    float* db = dout + (size_t)b * NN * NN;
    for (int ir = ir0; ir < 64; ir += 4) {
        int i = i0 + ir;
        float mi = mask[b * NN + i] * -1e-4f;
        float a = aval(ab[(size_t)i * NN + j0 + jc], mi, mj);
        db[(size_t)i * NN + j0 + jc] = a * (float)(dg - Xt[jc][ir]);
    }
}

// ---------------- d + transposed masked bf16 hi/lo attn ----------------
template <typename T>
__global__ void k_d2(const T* __restrict__ M, const double* __restrict__ Dg,
                     const float* __restrict__ adj, const float* __restrict__ mask,
                     float* __restrict__ dout,
                     unsigned short* __restrict__ ATh, unsigned short* __restrict__ ATl) {
    int b = blockIdx.x, i0 = blockIdx.y * 64, j0 = blockIdx.z * 64;
    __shared__ double Xt[64][65];
    __shared__ float dt[64][65];
    int t = threadIdx.x, ii = t & 63, jj0 = t >> 6;
    const T* Mb = M + (size_t)b * NN * NN;
    for (int jj = jj0; jj < 64; jj += 4)
        Xt[jj][ii] = (double)Mb[(size_t)(j0 + jj) * NN + i0 + ii];
    __syncthreads();
    int jc = t & 63, ir0 = t >> 6;
    float mj = mask[b * NN + j0 + jc] * -1e-4f;
    double dg = Dg[b * NN + j0 + jc];
    const float* ab = adj + (size_t)b * NN * NN;
    float* db = dout + (size_t)b * NN * NN;
    for (int ir = ir0; ir < 64; ir += 4) {
        int i = i0 + ir;
        float mi = mask[b * NN + i] * -1e-4f;
        float a = aval(ab[(size_t)i * NN + j0 + jc], mi, mj);
        float v = a * (float)(dg - Xt[jc][ir]);
        db[(size_t)i * NN + j0 + jc] = v;
        dt[ir][jc] = v;
    }
    __syncthreads();
    // AT[b][q=j0+ql][k=i0+kl] = valid_k ? dt[kl][ql] : 0   (bf16 hi/lo)
    int ql = t >> 2, kq = t & 3;
    us8 vh0, vh1, vl0, vl1;
#pragma unroll
    for (int u = 0; u < 16; ++u) {
        int k = kq * 16 + u;
        float mk = mask[b * NN + i0 + k] * -1e-4f;
        float v = (mk > 0.5f) ? 0.f : dt[k][ql];
        unsigned short h = f2bf(v);
        unsigned short l = f2bf(v - bf2f(h));
        if (u < 8) { vh0[u] = h; vl0[u] = l; } else { vh1[u - 8] = h; vl1[u - 8] = l; }
    }
    size_t ao = ((size_t)b * NN + j0 + ql) * NN + i0 + kq * 16;
    *(us8*)&ATh[ao] = vh0; *(us8*)&ATh[ao + 8] = vh1;
    *(us8*)&ATl[ao] = vl0; *(us8*)&ATl[ao + 8] = vl1;
}

// ---------------- x -> transposed bf16 hi/lo ----------------
__global__ void k_cvt_x(const float* __restrict__ x,
                        unsigned short* __restrict__ XTh, unsigned short* __restrict__ XTl) {
    int b = blockIdx.x, k0 = blockIdx.y * 64, c0 = blockIdx.z * 64;
    __shared__ float xs[64][65];
    int t = threadIdx.x;
#pragma unroll
    for (int rep = 0; rep < 16; ++rep) {
        int e = rep * 256 + t;
        int row = e >> 6, col = e & 63;
        xs[row][col] = x[((size_t)b * NN + k0 + row) * DD + c0 + col];
    }
    __syncthreads();
    int cl = t >> 2, kq = t & 3;
    us8 vh0, vh1, vl0, vl1;
#pragma unroll
    for (int u = 0; u < 16; ++u) {
        int k = kq * 16 + u;
        float v = xs[k][cl];
        unsigned short h = f2bf(v);
        unsigned short l = f2bf(v - bf2f(h));
        if (u < 8) { vh0[u] = h; vl0[u] = l; } else { vh1[u - 8] = h; vl1[u - 8] = l; }
    }
    size_t ao = ((size_t)b * DD + c0 + cl) * NN + k0 + kq * 16;
    *(us8*)&XTh[ao] = vh0; *(us8*)&XTh[ao + 8] = vh1;
    *(us8*)&XTl[ao] = vl0; *(us8*)&XTl[ao + 8] = vl1;
}

// ---------------- context GEMM: MFMA bf16, Keff = 3*512 ----------------
__global__ __launch_bounds__(256) void k_ctx2(const unsigned short* __restrict__ ATh,
                                              const unsigned short* __restrict__ ATl,
                                              const unsigned short* __restrict__ XTh,
                                              const unsigned short* __restrict__ XTl,
                                              float* __restrict__ ctx) {
    __shared__ __align__(16) unsigned short As[128 * 64];
    __shared__ __align__(16) unsigned short Bs[128 * 64];
    int b = blockIdx.x;
    int bm = blockIdx.y * 128, bn = blockIdx.z * 128;
    int t = threadIdx.x, wid = t >> 6, lane = t & 63;
    f32x4 acc[4][4];
#pragma unroll
    for (int i = 0; i < 4; ++i)
#pragma unroll
        for (int j = 0; j < 4; ++j) acc[i][j] = (f32x4){0.f, 0.f, 0.f, 0.f};

    const unsigned short* Asrc[3] = {ATh, ATh, ATl};
    const unsigned short* Bsrc[3] = {XTh, XTl, XTh};

    for (int kt = 0; kt < 24; ++kt) {
        int p = kt >> 3, ki = (kt & 7) * 64;
        const unsigned short* Ag = Asrc[p] + ((size_t)b * NN + bm) * NN + ki;
        const unsigned short* Bg = Bsrc[p] + ((size_t)b * DD + bn) * NN + ki;
        __syncthreads();
#pragma unroll
        for (int it = 0; it < 4; ++it) {
            int chunk = it * 256 + wid * 64 + lane;
            int row = chunk >> 3;
            int lc = (chunk & 7) ^ (row & 7);
            gl_lds16(Ag + (size_t)row * NN + lc * 8, &As[(it * 256 + wid * 64) * 8]);
        }
#pragma unroll
        for (int it = 0; it < 4; ++it) {
            int chunk = it * 256 + wid * 64 + lane;
            int row = chunk >> 3;
            int lc = (chunk & 7) ^ (row & 7);
            gl_lds16(Bg + (size_t)row * NN + lc * 8, &Bs[(it * 256 + wid * 64) * 8]);
        }
        __syncthreads();
        int m0 = (wid >> 1) * 64, n0 = (wid & 1) * 64;
#pragma unroll
        for (int kk = 0; kk < 2; ++kk) {
            bf16x8 af[4], bfr[4];
            int kc = kk * 4 + (lane >> 4);
#pragma unroll
            for (int f = 0; f < 4; ++f) {
                int arow = m0 + f * 16 + (lane & 15);
                af[f] = *(const bf16x8*)&As[arow * 64 + ((kc ^ (arow & 7)) * 8)];
                int brow = n0 + f * 16 + (lane & 15);
                bfr[f] = *(const bf16x8*)&Bs[brow * 64 + ((kc ^ (brow & 7)) * 8)];
            }
#pragma unroll
            for (int fm = 0; fm < 4; ++fm)
#pragma unroll
                for (int fn = 0; fn < 4; ++fn)
                    acc[fm][fn] = __builtin_amdgcn_mfma_f32_16x16x32_bf16(af[fm], bfr[fn], acc[fm][fn], 0, 0, 0);
        }
    }
    int m0 = (wid >> 1) * 64, n0 = (wid & 1) * 64;
    float* cb = ctx + ((size_t)b * NN + bm + m0) * DD + bn + n0;
#pragma unroll
    for (int fm = 0; fm < 4; ++fm)
#pragma unroll
        for (int fn = 0; fn < 4; ++fn)
#pragma unroll
            for (int r = 0; r < 4; ++r) {
                int row = fm * 16 + (lane >> 4) * 4 + r;
                int col = fn * 16 + (lane & 15);
                cb[(size_t)row * DD + col] = acc[fm][fn][r];
            }
}

// ---------------- context (old, fallback) ----------------
__global__ void k_ctx(const float* __restrict__ dmat, const float* __restrict__ x,
                      const float* __restrict__ mask, float* __restrict__ ctx) {
    int b = blockIdx.x, i0 = blockIdx.y * 64, c0 = blockIdx.z * 64;
    __shared__ float At[32][65];
    __shared__ float Xl[32][65];
    int t = threadIdx.x;
    int tx = t & 15, ty = t >> 4;
    float acc[4][4] = {};
    const float* db = dmat + (size_t)b * NN * NN;
    const float* xb = x + (size_t)b * NN * DD;
    int li = t & 63, lk = t >> 6;
    for (int kt = 0; kt < NN; kt += 32) {
#pragma unroll
        for (int rep = 0; rep < 8; ++rep) {
            int kk = lk + rep * 4;
            float mk = mask[b * NN + kt + kk] * -1e-4f;
            float v = db[(size_t)(kt + kk) * NN + i0 + li];
            At[kk][li] = (mk > 0.5f) ? 0.f : v;
            Xl[kk][li] = xb[(size_t)(kt + kk) * DD + c0 + li];
        }
        __syncthreads();
        for (int kk = 0; kk < 32; ++kk) {
            float av[4], bv[4];
#pragma unroll
            for (int u = 0; u < 4; ++u) { av[u] = At[kk][ty * 4 + u]; bv[u] = Xl[kk][tx * 4 + u]; }
#pragma unroll
            for (int u = 0; u < 4; ++u)
#pragma unroll
                for (int v = 0; v < 4; ++v) acc[u][v] += av[u] * bv[v];
        }
        __syncthreads();
    }
    float* cb = ctx + (size_t)b * NN * DD;
#pragma unroll
    for (int u = 0; u < 4; ++u)
#pragma unroll
        for (int v = 0; v < 4; ++v)
            cb[(size_t)(i0 + ty * 4 + u) * DD + c0 + tx * 4 + v] = acc[u][v];
}

// ---------------- drivers ----------------
template <typename T>
static void run_old(const float* x, const float* adj, const float* mask,
                    const float* rlab, const int* rmask, const float* w, const float* br,
                    float* ctx, float* dmat, float* lossout,
                    char* ws, hipStream_t stream) {
    size_t off = 0;
    T* M  = (T*)(ws + off); off += (size_t)BB * NN * NN * sizeof(T);
    T* Cb = (T*)(ws + off); off += (size_t)BB * NN * KB * sizeof(T);
    T* Bb = (T*)(ws + off); off += (size_t)BB * KB * KB * sizeof(T);
    double* Lp = (double*)(ws + off); off += (size_t)BB * 4 * NN * 8;
    float* Rf  = (float*)(ws + off);  off += (size_t)BB * NN * 4;
    double* Dg = (double*)(ws + off); off += (size_t)BB * NN * 8;
    float* lossp = (float*)(ws + off);

    k_root<<<BB * NN / 4, 256, 0, stream>>>(x, mask, w, br, Rf);
    k_colsum<<<dim3(BB, 4), 512, 0, stream>>>(adj, mask, Lp);
    k_build<T><<<BB * NN, 512, 0, stream>>>(adj, mask, Rf, Lp, M);
    for (int s = 0; s < NSTEP; ++s) {
        int k0 = s * KB;
        k_savecol<T><<<BB * NN / 4, 256, 0, stream>>>(M, Cb, k0);
        k_invblk<T><<<BB, 256, 0, stream>>>(M, Bb, k0);
        k_pivrows<T><<<dim3(BB, 8), 256, 0, stream>>>(M, Bb, k0);
        k_update<T><<<dim3(BB, 8, 8), 256, 0, stream>>>(M, Cb, k0);
    }
    k_dgloss<T><<<BB * NN / 256, 256, 0, stream>>>(M, Rf, rlab, rmask, Dg, lossp);
    k_lossfin<<<1, 128, 0, stream>>>(lossp, lossout);
    k_d<T><<<dim3(BB, 8, 8), 256, 0, stream>>>(M, Dg, adj, mask, dmat);
    k_ctx<<<dim3(BB, 8, 12), 256, 0, stream>>>(dmat, x, mask, ctx);
}

static void run_new(const float* x, const float* adj, const float* mask,
                    const float* rlab, const int* rmask, const float* w, const float* br,
                    float* ctx, float* dmat, float* lossout,
                    char* ws, hipStream_t stream) {
    size_t off = 0;
    double* M  = (double*)(ws + off); off += (size_t)BB * NN * NN * 8;
    double* Cb = (double*)(ws + off); off += (size_t)BB * NN * KB * 8;
    double* Bb = (double*)(ws + off); off += (size_t)BB * KB * KB * 8;
    double* Lp = (double*)(ws + off); off += (size_t)BB * 4 * NN * 8;
    float* Rf  = (float*)(ws + off);  off += (size_t)BB * NN * 4;
    double* Dg = (double*)(ws + off); off += (size_t)BB * NN * 8;
    float* lossp = (float*)(ws + off); off += 4096;
    unsigned short* ATh = (unsigned short*)(ws + off); off += (size_t)BB * NN * NN * 2;
    unsigned short* ATl = (unsigned short*)(ws + off); off += (size_t)BB * NN * NN * 2;
    // XT aliases M (dead after k_d2/k_dgloss)
    unsigned short* XTh = (unsigned short*)(ws);
    unsigned short* XTl = (unsigned short*)(ws + (size_t)BB * DD * NN * 2);

    k_root<<<BB * NN / 4, 256, 0, stream>>>(x, mask, w, br, Rf);
    k_colsum<<<dim3(BB, 4), 512, 0, stream>>>(adj, mask, Lp);
    k_build<double><<<BB * NN, 512, 0, stream>>>(adj, mask, Rf, Lp, M);
    for (int s = 0; s < NSTEP; ++s) {
        int k0 = s * KB;
        k_savecol<double><<<BB * NN / 4, 256, 0, stream>>>(M, Cb, k0);
        k_invblk<double><<<BB, 256, 0, stream>>>(M, Bb, k0);
        k_pivrows<double><<<dim3(BB, 8), 256, 0, stream>>>(M, Bb, k0);
        k_update<double><<<dim3(BB, 8, 8), 256, 0, stream>>>(M, Cb, k0);
    }
    k_dgloss<double><<<BB * NN / 256, 256, 0, stream>>>(M, Rf, rlab, rmask, Dg, lossp);
    k_lossfin<<<1, 128, 0, stream>>>(lossp, lossout);
    k_d2<double><<<dim3(BB, 8, 8), 256, 0, stream>>>(M, Dg, adj, mask, dmat, ATh, ATl);
    k_cvt_x<<<dim3(BB, 8, 12), 256, 0, stream>>>(x, XTh, XTl);   // overwrites M region
    k_ctx2<<<dim3(BB, 4, 6), 256, 0, stream>>>(ATh, ATl, XTh, XTl, ctx);
}

extern "C" void kernel_launch(void* const* d_in, const int* in_sizes, int n_in,
                              void* d_out, int out_size, void* d_ws, size_t ws_size,
                              hipStream_t stream) {
    const float* x    = (const float*)d_in[0];
    const float* adj  = (const float*)d_in[1];
    const float* mask = (const float*)d_in[2];
    const float* rlab = (const float*)d_in[3];
    const int*   rmask= (const int*)d_in[4];
    const float* w    = (const float*)d_in[5];
    const float* br   = (const float*)d_in[6];
    float* out = (float*)d_out;
    float* ctx = out;
    float* dmat = out + (size_t)BB * NN * DD;
    float* lossout = dmat + (size_t)BB * NN * NN;
    char* ws = (char*)d_ws;

    size_t base = (size_t)BB * NN * NN * 8 + (size_t)BB * NN * KB * 8 + (size_t)BB * KB * KB * 8
                + (size_t)BB * 4 * NN * 8 + (size_t)BB * NN * 4 + (size_t)BB * NN * 8 + 4096;
    size_t need_new = base + (size_t)BB * NN * NN * 4;   // + ATh/ATl
    if (ws_size >= need_new)
        run_new(x, adj, mask, rlab, rmask, w, br, ctx, dmat, lossout, ws, stream);
    else if (ws_size >= base)
        run_old<double>(x, adj, mask, rlab, rmask, w, br, ctx, dmat, lossout, ws, stream);
    else
        run_old<float>(x, adj, mask, rlab, rmask, w, br, ctx, dmat, lossout, ws, stream);
}